// Round 15
// baseline (242.728 us; speedup 1.0000x reference)
//
#include <hip/hip_runtime.h>

#define DEV __device__ __forceinline__

// counted waitcnt + raw barrier (T4)
#define VMCNT(N) asm volatile("s_waitcnt vmcnt(" #N ")" ::: "memory")
#define SBAR()                              \
  do {                                      \
    __builtin_amdgcn_sched_barrier(0);      \
    __builtin_amdgcn_s_barrier();           \
    __builtin_amdgcn_sched_barrier(0);      \
  } while (0)

typedef __attribute__((ext_vector_type(4))) float f32x4;
typedef __attribute__((ext_vector_type(16))) float f32x16;
typedef __attribute__((ext_vector_type(4))) float fl4;
typedef __attribute__((ext_vector_type(8))) __bf16 bf16x8;
typedef __attribute__((ext_vector_type(2))) __bf16 bf16x2;
typedef __attribute__((ext_vector_type(4))) unsigned short us4;
typedef __attribute__((ext_vector_type(8))) unsigned short us8;
typedef __attribute__((ext_vector_type(4))) unsigned int ui4;

DEV unsigned short f2bf(float f) {
  unsigned u = __builtin_bit_cast(unsigned, f);
  u += 0x7fffu + ((u >> 16) & 1u);
  return (unsigned short)(u >> 16);
}
DEV float bf2f(unsigned short h) {
  unsigned u = ((unsigned)h) << 16;
  return __builtin_bit_cast(float, u);
}

DEV void load_lds16(const void* g, void* l) {
  __builtin_amdgcn_global_load_lds(
      (const __attribute__((address_space(1))) void*)g,
      (__attribute__((address_space(3))) void*)l, 16, 0, 0);
}

DEV unsigned pk2(float a, float b) {  // pack 2 fp32 -> 2 bf16 (RNE)
  bf16x2 t;
  t[0] = (__bf16)a; t[1] = (__bf16)b;
  return __builtin_bit_cast(unsigned, t);
}
DEV bf16x8 frag4(unsigned a, unsigned b, unsigned c, unsigned d) {
  ui4 u; u[0] = a; u[1] = b; u[2] = c; u[3] = d;
  return __builtin_bit_cast(bf16x8, u);
}
// single-instruction 2^x (exp2f w/o fast-math lowers to the ocml libcall path)
DEV float fexp2(float x) {
  float r;
  asm("v_exp_f32 %0, %1" : "=v"(r) : "v"(x));
  return r;
}

// ---------------- fused prep: convert x | rope table | weight transpose ------
__global__ void k_prep(const float* __restrict__ x, unsigned short* __restrict__ xb,
                       float2* __restrict__ tab,
                       const float* __restrict__ W0, const float* __restrict__ W1,
                       const float* __restrict__ W2, const float* __restrict__ W3,
                       unsigned short* __restrict__ T0, unsigned short* __restrict__ T1,
                       unsigned short* __restrict__ T2, unsigned short* __restrict__ T3) {
  __shared__ float tile[64][65];
  const int bx = blockIdx.x, tid = threadIdx.x;
  if (bx < 4096) {  // convert x -> bf16
    size_t i = (size_t)bx * 256 + tid;
    const float* p = x + i * 8;
    fl4 a = *(const fl4*)p;
    fl4 b = *(const fl4*)(p + 4);
    us8 o;
    o[0] = f2bf(a[0]); o[1] = f2bf(a[1]); o[2] = f2bf(a[2]); o[3] = f2bf(a[3]);
    o[4] = f2bf(b[0]); o[5] = f2bf(b[1]); o[6] = f2bf(b[2]); o[7] = f2bf(b[3]);
    *(us8*)(xb + i * 8) = o;
  } else if (bx < 4352) {  // rope table: tab[pos*32+t] = {cos,sin}
    int i = (bx - 4096) * 256 + tid;
    int pos = i >> 5, t = i & 31;
    float ang = (float)pos * exp2f(-(float)t * 0.41524101186092029f);
    float sn, cs;
    __sincosf(ang, &sn, &cs);
    tab[i] = make_float2(cs, sn);
  } else {  // weight transpose -> bf16 (W KxN -> T NxK)
    int bid = bx - 4352;
    const float* W; unsigned short* T;
    switch (bid >> 8) {
      case 0: W = W0; T = T0; break;
      case 1: W = W1; T = T1; break;
      case 2: W = W2; T = T2; break;
      default: W = W3; T = T3; break;
    }
    int bxy = bid & 255;
    int k0 = (bxy >> 4) * 64, n0 = (bxy & 15) * 64;
    int tr = tid >> 4, tc = (tid & 15) * 4;
#pragma unroll
    for (int p = 0; p < 4; ++p) {
      int r = p * 16 + tr;
      fl4 v = *(const fl4*)&W[(size_t)(k0 + r) * 1024 + n0 + tc];
#pragma unroll
      for (int j = 0; j < 4; ++j) tile[r][tc + j] = v[j];
    }
    __syncthreads();
#pragma unroll
    for (int p = 0; p < 4; ++p) {
      int rr = p * 16 + tr;
      us4 o;
#pragma unroll
      for (int j = 0; j < 4; ++j) o[j] = f2bf(tile[tc + j][rr]);
      *(us4*)&T[(size_t)(n0 + rr) * 1024 + k0 + tc] = o;
    }
  }
}

// ---------------- fused QKV GEMM: gemm_o-structure clone ---------------------
// 128x128 tile, 4 waves (2x2), acc[4][4], 3 static buffers (48KB), counted
// VMCNT(4), grid 1536 (XCD-swizzled) -> 3 blocks/CU. Epilogue by segment:
// bn 0-7 -> Q (rope * log2e/32), 8-15 -> K (rope), 16-23 -> Vt (transposed).
__global__ __launch_bounds__(256, 3) void k_gemm_qkv(
    const unsigned short* __restrict__ A, const unsigned short* __restrict__ Bt,
    const float* __restrict__ bq, const float* __restrict__ bk, const float* __restrict__ bv,
    const float2* __restrict__ tab,
    unsigned short* __restrict__ Qb, unsigned short* __restrict__ Kb,
    unsigned short* __restrict__ Vt) {
  __shared__ alignas(16) unsigned short As[3][4096];
  __shared__ alignas(16) unsigned short Bs[3][4096];
  const int tid = threadIdx.x, w = tid >> 6, l = tid & 63;
  const int lg = l >> 4, lm = l & 15;
  const int sw = (blockIdx.x & 7) * 192 + (blockIdx.x >> 3);  // XCD swizzle, 1536=8x192
  const int bm = sw / 24, bn = sw % 24;  // bm in [0,64), bn in [0,24)
  const int wr = w >> 1, wc = w & 1;
  f32x4 acc[4][4] = {};
  auto stage = [&](int buf, int kt) {
#pragma unroll
    for (int p = 0; p < 2; ++p) {
      int cb = (w * 2 + p) * 64, c = cb + l, g = c >> 7, r = c & 127;
      load_lds16(A + (size_t)(bm * 128 + r) * 1024 + kt * 32 + g * 8, &As[buf][cb * 8]);
      load_lds16(Bt + (size_t)(bn * 128 + r) * 1024 + kt * 32 + g * 8, &Bs[buf][cb * 8]);
    }
  };
  stage(0, 0);
  stage(1, 1);
  int cur = 0;
  for (int kt = 0; kt < 32; ++kt) {
    if (kt == 31) { VMCNT(0); } else { VMCNT(4); }
    SBAR();
    if (kt + 2 < 32) {
      int nb = cur + 2; if (nb >= 3) nb -= 3;
      stage(nb, kt + 2);
    }
    bf16x8 af[4], bfr[4];
#pragma unroll
    for (int m = 0; m < 4; ++m)
      af[m] = *(const bf16x8*)&As[cur][(lg * 128 + wr * 64 + m * 16 + lm) * 8];
#pragma unroll
    for (int n = 0; n < 4; ++n)
      bfr[n] = *(const bf16x8*)&Bs[cur][(lg * 128 + wc * 64 + n * 16 + lm) * 8];
    __builtin_amdgcn_s_setprio(1);
#pragma unroll
    for (int m = 0; m < 4; ++m)
#pragma unroll
      for (int n = 0; n < 4; ++n)
        acc[m][n] = __builtin_amdgcn_mfma_f32_16x16x32_bf16(af[m], bfr[n], acc[m][n], 0, 0, 0);
    __builtin_amdgcn_s_setprio(0);
    cur = (cur == 2) ? 0 : cur + 1;
  }
  const int row0 = bm * 128 + wr * 64;
  const int col0 = bn * 128 + wc * 64;  // global col in [0,3072)
  const int seg = bn >> 3;              // 0=Q, 1=K, 2=V
  if (seg == 2) {
#pragma unroll
    for (int n = 0; n < 4; ++n) {
      int hd = (col0 & 1023) + n * 16 + lm;
      float bvv = bv[hd];
#pragma unroll
      for (int m = 0; m < 4; ++m) {
        int row = row0 + m * 16 + lg * 4;
        int bb = row >> 11, s = row & 2047;
        us4 o;
#pragma unroll
        for (int i = 0; i < 4; ++i) o[i] = f2bf(acc[m][n][i] + bvv);
        *(us4*)&Vt[((size_t)(bb * 1024 + hd)) * 2048 + s] = o;
      }
    }
  } else {
    const float* bias = seg ? bk : bq;
    unsigned short* Dst = seg ? Kb : Qb;
    const float qsc = seg ? 1.0f : 0.045084220027780106f;  // log2(e)/32 folded into Q
#pragma unroll
    for (int n = 0; n < 4; ++n) {
      int ch = (col0 & 1023) + n * 16 + lm;
      int t = (ch & 63) >> 1;
      float bvv = bias[ch];
#pragma unroll
      for (int m = 0; m < 4; ++m) {
#pragma unroll
        for (int i = 0; i < 4; ++i) {
          int row = row0 + m * 16 + lg * 4 + i;
          int pos = row & 2047;
          float xv = bf2f(f2bf(acc[m][n][i] + bvv));  // bf16-pre-round (matches ref floor)
          float xp = __shfl_xor(xv, 1, 64);
          float2 cs = tab[pos * 32 + t];
          float out = (lm & 1) ? (xv * cs.x + xp * cs.y) * qsc
                               : (xv * cs.x - xp * cs.y) * qsc;
          Dst[(size_t)row * 1024 + ch] = f2bf(out);
        }
      }
    }
  }
}

// ---------------- output GEMM: fp32 out + bias; counted-vmcnt pipeline ------
__global__ __launch_bounds__(256, 3) void k_gemm_o(const unsigned short* __restrict__ A,
                                                   const unsigned short* __restrict__ Bt,
                                                   const float* __restrict__ bias,
                                                   float* __restrict__ C) {
  __shared__ alignas(16) unsigned short As[3][4096];
  __shared__ alignas(16) unsigned short Bs[3][4096];
  const int tid = threadIdx.x, w = tid >> 6, l = tid & 63;
  const int lg = l >> 4, lm = l & 15;
  const int sw = (blockIdx.x & 7) * 64 + (blockIdx.x >> 3);
  const int bm = sw >> 3, bn = sw & 7;
  const int wr = w >> 1, wc = w & 1;
  f32x4 acc[4][4] = {};
  auto stage = [&](int buf, int kt) {
#pragma unroll
    for (int p = 0; p < 2; ++p) {
      int cb = (w * 2 + p) * 64, c = cb + l, g = c >> 7, r = c & 127;
      load_lds16(A + (size_t)(bm * 128 + r) * 1024 + kt * 32 + g * 8, &As[buf][cb * 8]);
      load_lds16(Bt + (size_t)(bn * 128 + r) * 1024 + kt * 32 + g * 8, &Bs[buf][cb * 8]);
    }
  };
  stage(0, 0);
  stage(1, 1);
  int cur = 0;
  for (int kt = 0; kt < 32; ++kt) {
    if (kt == 31) { VMCNT(0); } else { VMCNT(4); }
    SBAR();
    if (kt + 2 < 32) {
      int nb = cur + 2; if (nb >= 3) nb -= 3;
      stage(nb, kt + 2);
    }
    bf16x8 af[4], bfr[4];
#pragma unroll
    for (int m = 0; m < 4; ++m)
      af[m] = *(const bf16x8*)&As[cur][(lg * 128 + wr * 64 + m * 16 + lm) * 8];
#pragma unroll
    for (int n = 0; n < 4; ++n)
      bfr[n] = *(const bf16x8*)&Bs[cur][(lg * 128 + wc * 64 + n * 16 + lm) * 8];
    __builtin_amdgcn_s_setprio(1);
#pragma unroll
    for (int m = 0; m < 4; ++m)
#pragma unroll
      for (int n = 0; n < 4; ++n)
        acc[m][n] = __builtin_amdgcn_mfma_f32_16x16x32_bf16(af[m], bfr[n], acc[m][n], 0, 0, 0);
    __builtin_amdgcn_s_setprio(0);
    cur = (cur == 2) ? 0 : cur + 1;
  }
  const int row0 = bm * 128 + wr * 64, col0 = bn * 128 + wc * 64;
#pragma unroll
  for (int n = 0; n < 4; ++n) {
    int col = col0 + n * 16 + lm;
    float bv = bias[col];
#pragma unroll
    for (int m = 0; m < 4; ++m) {
      int row = row0 + m * 16 + lg * 4;
#pragma unroll
      for (int i = 0; i < 4; ++i)
        C[(size_t)(row + i) * 1024 + col] = acc[m][n][i] + bv;
    }
  }
}

// ---------------- flash attention (round-11-verbatim) ------------------------
__global__ __launch_bounds__(256, 4) void k_attn(const unsigned short* __restrict__ Q,
                                                 const unsigned short* __restrict__ K,
                                                 const unsigned short* __restrict__ Vt,
                                                 unsigned short* __restrict__ O) {
  __shared__ alignas(16) unsigned short Ks[2][4096];  // [g=kb*4+dc][lane][8]
  __shared__ alignas(16) unsigned short Vs[2][4096];  // [g=kchunk*2+dblk][lane][8]
  const int tid = threadIdx.x, w = tid >> 6, l = tid & 63;
  const int lq = l & 31, hi = l >> 5;
  const int bid = (blockIdx.x & 7) * 128 + (blockIdx.x >> 3);  // XCD swizzle
  const int qt = bid & 15, h = (bid >> 4) & 15, b = bid >> 8;
  const int qrow = qt * 128 + w * 32 + lq;

  const unsigned short* qp = Q + ((size_t)(b * 2048 + qrow)) * 1024 + h * 64 + hi * 8;
  bf16x8 qf[4];
#pragma unroll
  for (int dc = 0; dc < 4; ++dc) qf[dc] = *(const bf16x8*)(qp + dc * 16);

  const unsigned short* Kbase = K + ((size_t)(b * 2048)) * 1024 + h * 64;
  const unsigned short* Vbase = Vt + ((size_t)((b * 16 + h) * 64)) * 2048;
  const int g0 = tid >> 6, ll = tid & 63;
  const size_t koff = ((size_t)((g0 >> 2) * 32 + (ll & 31))) * 1024 + (g0 & 3) * 16 + (ll >> 5) * 8;
  const size_t voff = ((size_t)((g0 & 1) * 32 + (ll & 31))) * 2048 + (g0 >> 1) * 16 + (ll >> 5) * 8;

  auto stageKV = [&](int buf, int tt) {
    const size_t kb = (size_t)(tt * 64) * 1024;
    load_lds16(Kbase + kb + koff, &Ks[buf][tid * 8]);
    load_lds16(Kbase + kb + koff + (size_t)32 * 1024, &Ks[buf][(tid + 256) * 8]);
    load_lds16(Vbase + tt * 64 + voff, &Vs[buf][tid * 8]);
    load_lds16(Vbase + tt * 64 + voff + 32, &Vs[buf][(tid + 256) * 8]);
  };

  float L = 0.0f;
  f32x16 Oa0 = {}, Oa1 = {};

  stageKV(0, 0);
  __syncthreads();

  for (int t = 0; t < 32; ++t) {
    const int cur = t & 1;
    if (t < 31) stageKV(cur ^ 1, t + 1);  // issue early; drain at iter end
    // S[key][query]
    f32x16 s0 = {}, s1 = {};
    const unsigned short* Kc = Ks[cur];
    __builtin_amdgcn_s_setprio(1);
#pragma unroll
    for (int dc = 0; dc < 4; ++dc) {
      bf16x8 kf0 = *(const bf16x8*)&Kc[(dc * 64 + l) * 8];
      bf16x8 kf1 = *(const bf16x8*)&Kc[((4 + dc) * 64 + l) * 8];
      s0 = __builtin_amdgcn_mfma_f32_32x32x16_bf16(kf0, qf[dc], s0, 0, 0, 0);
      s1 = __builtin_amdgcn_mfma_f32_32x32x16_bf16(kf1, qf[dc], s1, 0, 0, 0);
    }
    __builtin_amdgcn_s_setprio(0);
    // p = 2^s directly — single v_exp_f32 per element (scores bounded, no shift)
#pragma unroll
    for (int r = 0; r < 16; ++r) s0[r] = fexp2(s0[r]);
#pragma unroll
    for (int r = 0; r < 16; ++r) s1[r] = fexp2(s1[r]);
    // balanced tree sum
    float q8[8];
#pragma unroll
    for (int j = 0; j < 8; ++j) q8[j] = (s0[j] + s0[j + 8]) + (s1[j] + s1[j + 8]);
#pragma unroll
    for (int j = 0; j < 4; ++j) q8[j] += q8[j + 4];
    float ls = (q8[0] + q8[1]) + (q8[2] + q8[3]);
    ls += __shfl_xor(ls, 32, 64);
    L += ls;
    // pack P to bf16 pairs
    unsigned w0[8], w1[8];
#pragma unroll
    for (int j = 0; j < 8; ++j) {
      w0[j] = pk2(s0[2 * j], s0[2 * j + 1]);
      w1[j] = pk2(s1[2 * j], s1[2 * j + 1]);
    }
    // exchange halves with lane^32 to build B-frags
    unsigned ra = __shfl_xor(hi ? w0[0] : w0[2], 32, 64);
    unsigned rb = __shfl_xor(hi ? w0[1] : w0[3], 32, 64);
    unsigned rc = __shfl_xor(hi ? w0[4] : w0[6], 32, 64);
    unsigned rd = __shfl_xor(hi ? w0[5] : w0[7], 32, 64);
    unsigned re = __shfl_xor(hi ? w1[0] : w1[2], 32, 64);
    unsigned rf = __shfl_xor(hi ? w1[1] : w1[3], 32, 64);
    unsigned rg = __shfl_xor(hi ? w1[4] : w1[6], 32, 64);
    unsigned rh = __shfl_xor(hi ? w1[5] : w1[7], 32, 64);
    bf16x8 pf0 = hi ? frag4(ra, rb, w0[2], w0[3]) : frag4(w0[0], w0[1], ra, rb);
    bf16x8 pf1 = hi ? frag4(rc, rd, w0[6], w0[7]) : frag4(w0[4], w0[5], rc, rd);
    bf16x8 pf2 = hi ? frag4(re, rf, w1[2], w1[3]) : frag4(w1[0], w1[1], re, rf);
    bf16x8 pf3 = hi ? frag4(rg, rh, w1[6], w1[7]) : frag4(w1[4], w1[5], rg, rh);
    // O^T[d][query] += V^T[d][key] * P[key][query]
    const unsigned short* Vc = Vs[cur];
    __builtin_amdgcn_s_setprio(1);
    {
      bf16x8 v0 = *(const bf16x8*)&Vc[(0 * 64 + l) * 8];
      bf16x8 v1 = *(const bf16x8*)&Vc[(1 * 64 + l) * 8];
      Oa0 = __builtin_amdgcn_mfma_f32_32x32x16_bf16(v0, pf0, Oa0, 0, 0, 0);
      Oa1 = __builtin_amdgcn_mfma_f32_32x32x16_bf16(v1, pf0, Oa1, 0, 0, 0);
      v0 = *(const bf16x8*)&Vc[(2 * 64 + l) * 8];
      v1 = *(const bf16x8*)&Vc[(3 * 64 + l) * 8];
      Oa0 = __builtin_amdgcn_mfma_f32_32x32x16_bf16(v0, pf1, Oa0, 0, 0, 0);
      Oa1 = __builtin_amdgcn_mfma_f32_32x32x16_bf16(v1, pf1, Oa1, 0, 0, 0);
      v0 = *(const bf16x8*)&Vc[(4 * 64 + l) * 8];
      v1 = *(const bf16x8*)&Vc[(5 * 64 + l) * 8];
      Oa0 = __builtin_amdgcn_mfma_f32_32x32x16_bf16(v0, pf2, Oa0, 0, 0, 0);
      Oa1 = __builtin_amdgcn_mfma_f32_32x32x16_bf16(v1, pf2, Oa1, 0, 0, 0);
      v0 = *(const bf16x8*)&Vc[(6 * 64 + l) * 8];
      v1 = *(const bf16x8*)&Vc[(7 * 64 + l) * 8];
      Oa0 = __builtin_amdgcn_mfma_f32_32x32x16_bf16(v0, pf3, Oa0, 0, 0, 0);
      Oa1 = __builtin_amdgcn_mfma_f32_32x32x16_bf16(v1, pf3, Oa1, 0, 0, 0);
    }
    __builtin_amdgcn_s_setprio(0);
    if (t < 31) __syncthreads();  // drains stage(t+1) + guards buffer reuse
  }
  const float inv = 1.0f / L;
  unsigned short* op = O + ((size_t)(b * 2048 + qrow)) * 1024 + h * 64;
#pragma unroll
  for (int gq = 0; gq < 4; ++gq) {
    const int d0 = 8 * gq + 4 * hi;
    us4 o0, o1;
#pragma unroll
    for (int i = 0; i < 4; ++i) {
      o0[i] = f2bf(Oa0[gq * 4 + i] * inv);
      o1[i] = f2bf(Oa1[gq * 4 + i] * inv);
    }
    *(us4*)&op[d0] = o0;
    *(us4*)&op[32 + d0] = o1;
  }
}

extern "C" void kernel_launch(void* const* d_in, const int* in_sizes, int n_in,
                              void* d_out, int out_size, void* d_ws, size_t ws_size,
                              hipStream_t stream) {
  const float* x  = (const float*)d_in[0];
  const float* Wq = (const float*)d_in[1];
  const float* bq = (const float*)d_in[2];
  const float* Wk = (const float*)d_in[3];
  const float* bk = (const float*)d_in[4];
  const float* Wv = (const float*)d_in[5];
  const float* bv = (const float*)d_in[6];
  const float* Wo = (const float*)d_in[7];
  const float* bo = (const float*)d_in[8];

  unsigned short* xb   = (unsigned short*)d_ws;             // 8192x1024 bf16
  unsigned short* Wqkv = xb + (size_t)8192 * 1024;          // 3072x1024 bf16 (Q;K;V rows)
  unsigned short* WoT  = Wqkv + (size_t)3072 * 1024;        // 1024x1024
  unsigned short* Qb   = WoT + (size_t)1024 * 1024;         // 8192x1024
  unsigned short* Kb   = Qb + (size_t)8192 * 1024;
  unsigned short* Vt   = Kb + (size_t)8192 * 1024;          // [b][h*64+d][2048]
  unsigned short* Ib   = Vt + (size_t)8192 * 1024;          // attn out
  float2* tab = (float2*)Ib;  // 512KB rope table; dead before k_attn overwrites Ib

  k_prep<<<5376, 256, 0, stream>>>(x, xb, tab, Wq, Wk, Wv, Wo,
                                   Wqkv, Wqkv + (size_t)1024 * 1024,
                                   Wqkv + (size_t)2048 * 1024, WoT);
  k_gemm_qkv<<<1536, 256, 0, stream>>>(xb, Wqkv, bq, bk, bv, tab, Qb, Kb, Vt);
  k_attn<<<1024, 256, 0, stream>>>(Qb, Kb, Vt, Ib);
  k_gemm_o<<<512, 256, 0, stream>>>(Ib, WoT, bo, (float*)d_out);
}

// Round 16
// 233.202 us; speedup vs baseline: 1.0408x; 1.0408x over previous
//
#include <hip/hip_runtime.h>

#define DEV __device__ __forceinline__

// counted waitcnt (memory clobber = compiler fence for memory ops)
#define VMCNT(N) asm volatile("s_waitcnt vmcnt(" #N ")" ::: "memory")
// light barrier: HW barrier + compiler MEMORY fence only (no sched_barrier(0)
// order-pinning — m141: mask-0 fences cap GEMMs at ~510 TF by defeating the
// scheduler's own pipelining). Memory ops cannot cross; VALU/addressing can.
#define SBARL() asm volatile("s_barrier" ::: "memory")

typedef __attribute__((ext_vector_type(4))) float f32x4;
typedef __attribute__((ext_vector_type(16))) float f32x16;
typedef __attribute__((ext_vector_type(4))) float fl4;
typedef __attribute__((ext_vector_type(8))) __bf16 bf16x8;
typedef __attribute__((ext_vector_type(2))) __bf16 bf16x2;
typedef __attribute__((ext_vector_type(4))) unsigned short us4;
typedef __attribute__((ext_vector_type(8))) unsigned short us8;
typedef __attribute__((ext_vector_type(4))) unsigned int ui4;

DEV unsigned short f2bf(float f) {
  unsigned u = __builtin_bit_cast(unsigned, f);
  u += 0x7fffu + ((u >> 16) & 1u);
  return (unsigned short)(u >> 16);
}
DEV float bf2f(unsigned short h) {
  unsigned u = ((unsigned)h) << 16;
  return __builtin_bit_cast(float, u);
}

DEV void load_lds16(const void* g, void* l) {
  __builtin_amdgcn_global_load_lds(
      (const __attribute__((address_space(1))) void*)g,
      (__attribute__((address_space(3))) void*)l, 16, 0, 0);
}

DEV unsigned pk2(float a, float b) {  // pack 2 fp32 -> 2 bf16 (RNE)
  bf16x2 t;
  t[0] = (__bf16)a; t[1] = (__bf16)b;
  return __builtin_bit_cast(unsigned, t);
}
DEV bf16x8 frag4(unsigned a, unsigned b, unsigned c, unsigned d) {
  ui4 u; u[0] = a; u[1] = b; u[2] = c; u[3] = d;
  return __builtin_bit_cast(bf16x8, u);
}
// single-instruction 2^x (exp2f w/o fast-math lowers to the ocml libcall path)
DEV float fexp2(float x) {
  float r;
  asm("v_exp_f32 %0, %1" : "=v"(r) : "v"(x));
  return r;
}

// ---------------- fused prep: convert x | rope table | weight transpose ------
__global__ void k_prep(const float* __restrict__ x, unsigned short* __restrict__ xb,
                       float2* __restrict__ tab,
                       const float* __restrict__ W0, const float* __restrict__ W1,
                       const float* __restrict__ W2, const float* __restrict__ W3,
                       unsigned short* __restrict__ T0, unsigned short* __restrict__ T1,
                       unsigned short* __restrict__ T2, unsigned short* __restrict__ T3) {
  __shared__ float tile[64][65];
  const int bx = blockIdx.x, tid = threadIdx.x;
  if (bx < 4096) {  // convert x -> bf16
    size_t i = (size_t)bx * 256 + tid;
    const float* p = x + i * 8;
    fl4 a = *(const fl4*)p;
    fl4 b = *(const fl4*)(p + 4);
    us8 o;
    o[0] = f2bf(a[0]); o[1] = f2bf(a[1]); o[2] = f2bf(a[2]); o[3] = f2bf(a[3]);
    o[4] = f2bf(b[0]); o[5] = f2bf(b[1]); o[6] = f2bf(b[2]); o[7] = f2bf(b[3]);
    *(us8*)(xb + i * 8) = o;
  } else if (bx < 4352) {  // rope table: tab[pos*32+t] = {cos,sin}
    int i = (bx - 4096) * 256 + tid;
    int pos = i >> 5, t = i & 31;
    float ang = (float)pos * exp2f(-(float)t * 0.41524101186092029f);
    float sn, cs;
    __sincosf(ang, &sn, &cs);
    tab[i] = make_float2(cs, sn);
  } else {  // weight transpose -> bf16 (W KxN -> T NxK)
    int bid = bx - 4352;
    const float* W; unsigned short* T;
    switch (bid >> 8) {
      case 0: W = W0; T = T0; break;
      case 1: W = W1; T = T1; break;
      case 2: W = W2; T = T2; break;
      default: W = W3; T = T3; break;
    }
    int bxy = bid & 255;
    int k0 = (bxy >> 4) * 64, n0 = (bxy & 15) * 64;
    int tr = tid >> 4, tc = (tid & 15) * 4;
#pragma unroll
    for (int p = 0; p < 4; ++p) {
      int r = p * 16 + tr;
      fl4 v = *(const fl4*)&W[(size_t)(k0 + r) * 1024 + n0 + tc];
#pragma unroll
      for (int j = 0; j < 4; ++j) tile[r][tc + j] = v[j];
    }
    __syncthreads();
#pragma unroll
    for (int p = 0; p < 4; ++p) {
      int rr = p * 16 + tr;
      us4 o;
#pragma unroll
      for (int j = 0; j < 4; ++j) o[j] = f2bf(tile[tc + j][rr]);
      *(us4*)&T[(size_t)(n0 + rr) * 1024 + k0 + tc] = o;
    }
  }
}

// ---------------- fused QKV GEMM: 128x256, 4 waves, 2 blocks/CU (r14 base) --
// Light barriers (no sched_barrier pinning). K split into 32 halves; slot h%3
// (24KB). Per phase: VMCNT(6) retires half h; barrier; stage h+2; 12 ds_read;
// 32 MFMA. K ascending -> outputs bit-identical.
__global__ __launch_bounds__(256, 2) void k_gemm_qkv(
    const unsigned short* __restrict__ A, const unsigned short* __restrict__ Bt,
    const float* __restrict__ bq, const float* __restrict__ bk, const float* __restrict__ bv,
    const float2* __restrict__ tab,
    unsigned short* __restrict__ Qb, unsigned short* __restrict__ Kb,
    unsigned short* __restrict__ Vt) {
  extern __shared__ unsigned char lds[];
  const int tid = threadIdx.x, w = tid >> 6, l = tid & 63;
  const int lg = l >> 4, lm = l & 15;
  const int wc = w;  // 4 waves across N
  const int sw = (blockIdx.x & 7) * 96 + (blockIdx.x >> 3);  // XCD swizzle, 768=8x96
  const int bm = sw / 12, bn = sw % 12;  // bm in [0,64), bn in [0,12)

  f32x4 acc[8][4] = {};

  const unsigned short* Abase = A + (size_t)(bm * 128) * 1024;
  const unsigned short* Bbase = Bt + (size_t)(bn * 256) * 1024;

  // stage K-half h into slot h%3
  auto stageH = [&](int h) {
    unsigned char* db = lds + (h % 3) * 24576;
    const int r = tid & 127, gA = tid >> 7;
    const size_t ko = (size_t)h * 32;
    load_lds16(Abase + (size_t)r * 1024 + ko + gA * 8,       db + tid * 16);
    load_lds16(Abase + (size_t)r * 1024 + ko + (2 + gA) * 8, db + (tid + 256) * 16);
#pragma unroll
    for (int g = 0; g < 4; ++g)
      load_lds16(Bbase + (size_t)tid * 1024 + ko + g * 8, db + 8192 + (g * 256 + tid) * 16);
  };

  stageH(0);
  stageH(1);

  for (int h = 0; h < 32; ++h) {
    if (h == 31) { VMCNT(0); } else { VMCNT(6); }
    SBARL();
    if (h + 2 < 32) stageH(h + 2);
    const unsigned char* slot = lds + (h % 3) * 24576;
    const unsigned char* pa = slot + lg * 2048 + lm * 16;
    const unsigned char* pb = slot + 8192 + lg * 4096 + wc * 1024 + lm * 16;
    bf16x8 af[8], bfr[4];
#pragma unroll
    for (int m = 0; m < 8; ++m) af[m] = *(const bf16x8*)(pa + m * 256);
#pragma unroll
    for (int n = 0; n < 4; ++n) bfr[n] = *(const bf16x8*)(pb + n * 256);
    __builtin_amdgcn_s_setprio(1);
#pragma unroll
    for (int m = 0; m < 8; ++m)
#pragma unroll
      for (int n = 0; n < 4; ++n)
        acc[m][n] = __builtin_amdgcn_mfma_f32_16x16x32_bf16(af[m], bfr[n], acc[m][n], 0, 0, 0);
    __builtin_amdgcn_s_setprio(0);
  }

  const int row0 = bm * 128;
  const int col0 = bn * 256 + wc * 64;  // global col in [0,3072)
  const int seg = bn >> 2;              // 0=Q, 1=K, 2=V
  if (seg == 2) {
#pragma unroll
    for (int n = 0; n < 4; ++n) {
      int hd = (col0 & 1023) + n * 16 + lm;
      float bvv = bv[hd];
#pragma unroll
      for (int m = 0; m < 8; ++m) {
        int row = row0 + m * 16 + lg * 4;
        int bb = row >> 11, s = row & 2047;
        us4 o;
#pragma unroll
        for (int i = 0; i < 4; ++i) o[i] = f2bf(acc[m][n][i] + bvv);
        *(us4*)&Vt[((size_t)(bb * 1024 + hd)) * 2048 + s] = o;
      }
    }
  } else {
    const float* bias = seg ? bk : bq;
    unsigned short* Dst = seg ? Kb : Qb;
    const float qsc = seg ? 1.0f : 0.045084220027780106f;  // log2(e)/32 folded into Q
#pragma unroll
    for (int n = 0; n < 4; ++n) {
      int ch = (col0 & 1023) + n * 16 + lm;
      int t = (ch & 63) >> 1;
      float bvv = bias[ch];
#pragma unroll
      for (int m = 0; m < 8; ++m) {
#pragma unroll
        for (int i = 0; i < 4; ++i) {
          int row = row0 + m * 16 + lg * 4 + i;
          int pos = row & 2047;
          float xv = bf2f(f2bf(acc[m][n][i] + bvv));  // bf16-pre-round (matches ref floor)
          float xp = __shfl_xor(xv, 1, 64);
          float2 cs = tab[pos * 32 + t];
          float out = (lm & 1) ? (xv * cs.x + xp * cs.y) * qsc
                               : (xv * cs.x - xp * cs.y) * qsc;
          Dst[(size_t)row * 1024 + ch] = f2bf(out);
        }
      }
    }
  }
}

// ---------------- output GEMM: fp32 out + bias; light barriers --------------
__global__ __launch_bounds__(256, 3) void k_gemm_o(const unsigned short* __restrict__ A,
                                                   const unsigned short* __restrict__ Bt,
                                                   const float* __restrict__ bias,
                                                   float* __restrict__ C) {
  __shared__ alignas(16) unsigned short As[3][4096];
  __shared__ alignas(16) unsigned short Bs[3][4096];
  const int tid = threadIdx.x, w = tid >> 6, l = tid & 63;
  const int lg = l >> 4, lm = l & 15;
  const int sw = (blockIdx.x & 7) * 64 + (blockIdx.x >> 3);
  const int bm = sw >> 3, bn = sw & 7;
  const int wr = w >> 1, wc = w & 1;
  f32x4 acc[4][4] = {};
  auto stage = [&](int buf, int kt) {
#pragma unroll
    for (int p = 0; p < 2; ++p) {
      int cb = (w * 2 + p) * 64, c = cb + l, g = c >> 7, r = c & 127;
      load_lds16(A + (size_t)(bm * 128 + r) * 1024 + kt * 32 + g * 8, &As[buf][cb * 8]);
      load_lds16(Bt + (size_t)(bn * 128 + r) * 1024 + kt * 32 + g * 8, &Bs[buf][cb * 8]);
    }
  };
  stage(0, 0);
  stage(1, 1);
  int cur = 0;
  for (int kt = 0; kt < 32; ++kt) {
    if (kt == 31) { VMCNT(0); } else { VMCNT(4); }
    SBARL();
    if (kt + 2 < 32) {
      int nb = cur + 2; if (nb >= 3) nb -= 3;
      stage(nb, kt + 2);
    }
    bf16x8 af[4], bfr[4];
#pragma unroll
    for (int m = 0; m < 4; ++m)
      af[m] = *(const bf16x8*)&As[cur][(lg * 128 + wr * 64 + m * 16 + lm) * 8];
#pragma unroll
    for (int n = 0; n < 4; ++n)
      bfr[n] = *(const bf16x8*)&Bs[cur][(lg * 128 + wc * 64 + n * 16 + lm) * 8];
    __builtin_amdgcn_s_setprio(1);
#pragma unroll
    for (int m = 0; m < 4; ++m)
#pragma unroll
      for (int n = 0; n < 4; ++n)
        acc[m][n] = __builtin_amdgcn_mfma_f32_16x16x32_bf16(af[m], bfr[n], acc[m][n], 0, 0, 0);
    __builtin_amdgcn_s_setprio(0);
    cur = (cur == 2) ? 0 : cur + 1;
  }
  const int row0 = bm * 128 + wr * 64, col0 = bn * 128 + wc * 64;
#pragma unroll
  for (int n = 0; n < 4; ++n) {
    int col = col0 + n * 16 + lm;
    float bv = bias[col];
#pragma unroll
    for (int m = 0; m < 4; ++m) {
      int row = row0 + m * 16 + lg * 4;
#pragma unroll
      for (int i = 0; i < 4; ++i)
        C[(size_t)(row + i) * 1024 + col] = acc[m][n][i] + bv;
    }
  }
}

// ---------------- flash attention (round-11-verbatim) ------------------------
__global__ __launch_bounds__(256, 4) void k_attn(const unsigned short* __restrict__ Q,
                                                 const unsigned short* __restrict__ K,
                                                 const unsigned short* __restrict__ Vt,
                                                 unsigned short* __restrict__ O) {
  __shared__ alignas(16) unsigned short Ks[2][4096];  // [g=kb*4+dc][lane][8]
  __shared__ alignas(16) unsigned short Vs[2][4096];  // [g=kchunk*2+dblk][lane][8]
  const int tid = threadIdx.x, w = tid >> 6, l = tid & 63;
  const int lq = l & 31, hi = l >> 5;
  const int bid = (blockIdx.x & 7) * 128 + (blockIdx.x >> 3);  // XCD swizzle
  const int qt = bid & 15, h = (bid >> 4) & 15, b = bid >> 8;
  const int qrow = qt * 128 + w * 32 + lq;

  const unsigned short* qp = Q + ((size_t)(b * 2048 + qrow)) * 1024 + h * 64 + hi * 8;
  bf16x8 qf[4];
#pragma unroll
  for (int dc = 0; dc < 4; ++dc) qf[dc] = *(const bf16x8*)(qp + dc * 16);

  const unsigned short* Kbase = K + ((size_t)(b * 2048)) * 1024 + h * 64;
  const unsigned short* Vbase = Vt + ((size_t)((b * 16 + h) * 64)) * 2048;
  const int g0 = tid >> 6, ll = tid & 63;
  const size_t koff = ((size_t)((g0 >> 2) * 32 + (ll & 31))) * 1024 + (g0 & 3) * 16 + (ll >> 5) * 8;
  const size_t voff = ((size_t)((g0 & 1) * 32 + (ll & 31))) * 2048 + (g0 >> 1) * 16 + (ll >> 5) * 8;

  auto stageKV = [&](int buf, int tt) {
    const size_t kb = (size_t)(tt * 64) * 1024;
    load_lds16(Kbase + kb + koff, &Ks[buf][tid * 8]);
    load_lds16(Kbase + kb + koff + (size_t)32 * 1024, &Ks[buf][(tid + 256) * 8]);
    load_lds16(Vbase + tt * 64 + voff, &Vs[buf][tid * 8]);
    load_lds16(Vbase + tt * 64 + voff + 32, &Vs[buf][(tid + 256) * 8]);
  };

  float L = 0.0f;
  f32x16 Oa0 = {}, Oa1 = {};

  stageKV(0, 0);
  __syncthreads();

  for (int t = 0; t < 32; ++t) {
    const int cur = t & 1;
    if (t < 31) stageKV(cur ^ 1, t + 1);  // issue early; drain at iter end
    // S[key][query]
    f32x16 s0 = {}, s1 = {};
    const unsigned short* Kc = Ks[cur];
    __builtin_amdgcn_s_setprio(1);
#pragma unroll
    for (int dc = 0; dc < 4; ++dc) {
      bf16x8 kf0 = *(const bf16x8*)&Kc[(dc * 64 + l) * 8];
      bf16x8 kf1 = *(const bf16x8*)&Kc[((4 + dc) * 64 + l) * 8];
      s0 = __builtin_amdgcn_mfma_f32_32x32x16_bf16(kf0, qf[dc], s0, 0, 0, 0);
      s1 = __builtin_amdgcn_mfma_f32_32x32x16_bf16(kf1, qf[dc], s1, 0, 0, 0);
    }
    __builtin_amdgcn_s_setprio(0);
    // p = 2^s directly — single v_exp_f32 per element (scores bounded, no shift)
#pragma unroll
    for (int r = 0; r < 16; ++r) s0[r] = fexp2(s0[r]);
#pragma unroll
    for (int r = 0; r < 16; ++r) s1[r] = fexp2(s1[r]);
    // balanced tree sum
    float q8[8];
#pragma unroll
    for (int j = 0; j < 8; ++j) q8[j] = (s0[j] + s0[j + 8]) + (s1[j] + s1[j + 8]);
#pragma unroll
    for (int j = 0; j < 4; ++j) q8[j] += q8[j + 4];
    float ls = (q8[0] + q8[1]) + (q8[2] + q8[3]);
    ls += __shfl_xor(ls, 32, 64);
    L += ls;
    // pack P to bf16 pairs
    unsigned w0[8], w1[8];
#pragma unroll
    for (int j = 0; j < 8; ++j) {
      w0[j] = pk2(s0[2 * j], s0[2 * j + 1]);
      w1[j] = pk2(s1[2 * j], s1[2 * j + 1]);
    }
    // exchange halves with lane^32 to build B-frags
    unsigned ra = __shfl_xor(hi ? w0[0] : w0[2], 32, 64);
    unsigned rb = __shfl_xor(hi ? w0[1] : w0[3], 32, 64);
    unsigned rc = __shfl_xor(hi ? w0[4] : w0[6], 32, 64);
    unsigned rd = __shfl_xor(hi ? w0[5] : w0[7], 32, 64);
    unsigned re = __shfl_xor(hi ? w1[0] : w1[2], 32, 64);
    unsigned rf = __shfl_xor(hi ? w1[1] : w1[3], 32, 64);
    unsigned rg = __shfl_xor(hi ? w1[4] : w1[6], 32, 64);
    unsigned rh = __shfl_xor(hi ? w1[5] : w1[7], 32, 64);
    bf16x8 pf0 = hi ? frag4(ra, rb, w0[2], w0[3]) : frag4(w0[0], w0[1], ra, rb);
    bf16x8 pf1 = hi ? frag4(rc, rd, w0[6], w0[7]) : frag4(w0[4], w0[5], rc, rd);
    bf16x8 pf2 = hi ? frag4(re, rf, w1[2], w1[3]) : frag4(w1[0], w1[1], re, rf);
    bf16x8 pf3 = hi ? frag4(rg, rh, w1[6], w1[7]) : frag4(w1[4], w1[5], rg, rh);
    // O^T[d][query] += V^T[d][key] * P[key][query]
    const unsigned short* Vc = Vs[cur];
    __builtin_amdgcn_s_setprio(1);
    {
      bf16x8 v0 = *(const bf16x8*)&Vc[(0 * 64 + l) * 8];
      bf16x8 v1 = *(const bf16x8*)&Vc[(1 * 64 + l) * 8];
      Oa0 = __builtin_amdgcn_mfma_f32_32x32x16_bf16(v0, pf0, Oa0, 0, 0, 0);
      Oa1 = __builtin_amdgcn_mfma_f32_32x32x16_bf16(v1, pf0, Oa1, 0, 0, 0);
      v0 = *(const bf16x8*)&Vc[(2 * 64 + l) * 8];
      v1 = *(const bf16x8*)&Vc[(3 * 64 + l) * 8];
      Oa0 = __builtin_amdgcn_mfma_f32_32x32x16_bf16(v0, pf1, Oa0, 0, 0, 0);
      Oa1 = __builtin_amdgcn_mfma_f32_32x32x16_bf16(v1, pf1, Oa1, 0, 0, 0);
      v0 = *(const bf16x8*)&Vc[(4 * 64 + l) * 8];
      v1 = *(const bf16x8*)&Vc[(5 * 64 + l) * 8];
      Oa0 = __builtin_amdgcn_mfma_f32_32x32x16_bf16(v0, pf2, Oa0, 0, 0, 0);
      Oa1 = __builtin_amdgcn_mfma_f32_32x32x16_bf16(v1, pf2, Oa1, 0, 0, 0);
      v0 = *(const bf16x8*)&Vc[(6 * 64 + l) * 8];
      v1 = *(const bf16x8*)&Vc[(7 * 64 + l) * 8];
      Oa0 = __builtin_amdgcn_mfma_f32_32x32x16_bf16(v0, pf3, Oa0, 0, 0, 0);
      Oa1 = __builtin_amdgcn_mfma_f32_32x32x16_bf16(v1, pf3, Oa1, 0, 0, 0);
    }
    __builtin_amdgcn_s_setprio(0);
    if (t < 31) __syncthreads();  // drains stage(t+1) + guards buffer reuse
  }
  const float inv = 1.0f / L;
  unsigned short* op = O + ((size_t)(b * 2048 + qrow)) * 1024 + h * 64;
#pragma unroll
  for (int gq = 0; gq < 4; ++gq) {
    const int d0 = 8 * gq + 4 * hi;
    us4 o0, o1;
#pragma unroll
    for (int i = 0; i < 4; ++i) {
      o0[i] = f2bf(Oa0[gq * 4 + i] * inv);
      o1[i] = f2bf(Oa1[gq * 4 + i] * inv);
    }
    *(us4*)&op[d0] = o0;
    *(us4*)&op[32 + d0] = o1;
  }
}

extern "C" void kernel_launch(void* const* d_in, const int* in_sizes, int n_in,
                              void* d_out, int out_size, void* d_ws, size_t ws_size,
                              hipStream_t stream) {
  const float* x  = (const float*)d_in[0];
  const float* Wq = (const float*)d_in[1];
  const float* bq = (const float*)d_in[2];
  const float* Wk = (const float*)d_in[3];
  const float* bk = (const float*)d_in[4];
  const float* Wv = (const float*)d_in[5];
  const float* bv = (const float*)d_in[6];
  const float* Wo = (const float*)d_in[7];
  const float* bo = (const float*)d_in[8];

  unsigned short* xb   = (unsigned short*)d_ws;             // 8192x1024 bf16
  unsigned short* Wqkv = xb + (size_t)8192 * 1024;          // 3072x1024 bf16 (Q;K;V rows)
  unsigned short* WoT  = Wqkv + (size_t)3072 * 1024;        // 1024x1024
  unsigned short* Qb   = WoT + (size_t)1024 * 1024;         // 8192x1024
  unsigned short* Kb   = Qb + (size_t)8192 * 1024;
  unsigned short* Vt   = Kb + (size_t)8192 * 1024;          // [b][h*64+d][2048]
  unsigned short* Ib   = Vt + (size_t)8192 * 1024;          // attn out
  float2* tab = (float2*)Ib;  // 512KB rope table; dead before k_attn overwrites Ib

  k_prep<<<5376, 256, 0, stream>>>(x, xb, tab, Wq, Wk, Wv, Wo,
                                   Wqkv, Wqkv + (size_t)1024 * 1024,
                                   Wqkv + (size_t)2048 * 1024, WoT);
  k_gemm_qkv<<<768, 256, 73728, stream>>>(xb, Wqkv, bq, bk, bv, tab, Qb, Kb, Vt);
  k_attn<<<1024, 256, 0, stream>>>(Qb, Kb, Vt, Ib);
  k_gemm_o<<<512, 256, 0, stream>>>(Ib, WoT, bo, (float*)d_out);
}

// Round 17
// 227.091 us; speedup vs baseline: 1.0689x; 1.0269x over previous
//
#include <hip/hip_runtime.h>

#define DEV __device__ __forceinline__

// counted waitcnt (memory clobber = compiler fence for memory ops)
#define VMCNT(N) asm volatile("s_waitcnt vmcnt(" #N ")" ::: "memory")
// light barrier: HW barrier + compiler MEMORY fence (no sched_barrier pinning)
#define SBARL() asm volatile("s_barrier" ::: "memory")

typedef __attribute__((ext_vector_type(4))) float f32x4;
typedef __attribute__((ext_vector_type(16))) float f32x16;
typedef __attribute__((ext_vector_type(4))) float fl4;
typedef __attribute__((ext_vector_type(8))) __bf16 bf16x8;
typedef __attribute__((ext_vector_type(2))) __bf16 bf16x2;
typedef __attribute__((ext_vector_type(4))) unsigned short us4;
typedef __attribute__((ext_vector_type(8))) unsigned short us8;
typedef __attribute__((ext_vector_type(4))) unsigned int ui4;

DEV unsigned short f2bf(float f) {
  unsigned u = __builtin_bit_cast(unsigned, f);
  u += 0x7fffu + ((u >> 16) & 1u);
  return (unsigned short)(u >> 16);
}
DEV float bf2f(unsigned short h) {
  unsigned u = ((unsigned)h) << 16;
  return __builtin_bit_cast(float, u);
}

DEV void load_lds16(const void* g, void* l) {
  __builtin_amdgcn_global_load_lds(
      (const __attribute__((address_space(1))) void*)g,
      (__attribute__((address_space(3))) void*)l, 16, 0, 0);
}

DEV unsigned pk2(float a, float b) {  // pack 2 fp32 -> 2 bf16 (RNE)
  bf16x2 t;
  t[0] = (__bf16)a; t[1] = (__bf16)b;
  return __builtin_bit_cast(unsigned, t);
}
DEV bf16x8 frag4(unsigned a, unsigned b, unsigned c, unsigned d) {
  ui4 u; u[0] = a; u[1] = b; u[2] = c; u[3] = d;
  return __builtin_bit_cast(bf16x8, u);
}
// single-instruction 2^x
DEV float fexp2(float x) {
  float r;
  asm("v_exp_f32 %0, %1" : "=v"(r) : "v"(x));
  return r;
}

// ---------------- fused prep: convert x | rope table | weight transpose ------
__global__ void k_prep(const float* __restrict__ x, unsigned short* __restrict__ xb,
                       float2* __restrict__ tab,
                       const float* __restrict__ W0, const float* __restrict__ W1,
                       const float* __restrict__ W2, const float* __restrict__ W3,
                       unsigned short* __restrict__ T0, unsigned short* __restrict__ T1,
                       unsigned short* __restrict__ T2, unsigned short* __restrict__ T3) {
  __shared__ float tile[64][65];
  const int bx = blockIdx.x, tid = threadIdx.x;
  if (bx < 4096) {  // convert x -> bf16
    size_t i = (size_t)bx * 256 + tid;
    const float* p = x + i * 8;
    fl4 a = *(const fl4*)p;
    fl4 b = *(const fl4*)(p + 4);
    us8 o;
    o[0] = f2bf(a[0]); o[1] = f2bf(a[1]); o[2] = f2bf(a[2]); o[3] = f2bf(a[3]);
    o[4] = f2bf(b[0]); o[5] = f2bf(b[1]); o[6] = f2bf(b[2]); o[7] = f2bf(b[3]);
    *(us8*)(xb + i * 8) = o;
  } else if (bx < 4352) {  // rope table: tab[pos*32+t] = {cos,sin}
    int i = (bx - 4096) * 256 + tid;
    int pos = i >> 5, t = i & 31;
    float ang = (float)pos * exp2f(-(float)t * 0.41524101186092029f);
    float sn, cs;
    __sincosf(ang, &sn, &cs);
    tab[i] = make_float2(cs, sn);
  } else {  // weight transpose -> bf16 (W KxN -> T NxK)
    int bid = bx - 4352;
    const float* W; unsigned short* T;
    switch (bid >> 8) {
      case 0: W = W0; T = T0; break;
      case 1: W = W1; T = T1; break;
      case 2: W = W2; T = T2; break;
      default: W = W3; T = T3; break;
    }
    int bxy = bid & 255;
    int k0 = (bxy >> 4) * 64, n0 = (bxy & 15) * 64;
    int tr = tid >> 4, tc = (tid & 15) * 4;
#pragma unroll
    for (int p = 0; p < 4; ++p) {
      int r = p * 16 + tr;
      fl4 v = *(const fl4*)&W[(size_t)(k0 + r) * 1024 + n0 + tc];
#pragma unroll
      for (int j = 0; j < 4; ++j) tile[r][tc + j] = v[j];
    }
    __syncthreads();
#pragma unroll
    for (int p = 0; p < 4; ++p) {
      int rr = p * 16 + tr;
      us4 o;
#pragma unroll
      for (int j = 0; j < 4; ++j) o[j] = f2bf(tile[tc + j][rr]);
      *(us4*)&T[(size_t)(n0 + rr) * 1024 + k0 + tc] = o;
    }
  }
}

// ---------------- fused QKV GEMM: 128x256, 4 waves, 2 blocks/CU --------------
// Main loop = r16-verbatim. NEW epilogue: bounce acc through LDS (64KB
// [row:128][col:256] bf16) -> coalesced 16B stores. Q/K: rope applied after
// re-read (pairs adjacent in-thread -> no shfl); V: transposed gather -> 16B
// stores along s (kills the 8B/4KB-stride write amplification). Rope float
// expression order preserved -> bit-identical outputs.
__global__ __launch_bounds__(256, 2) void k_gemm_qkv(
    const unsigned short* __restrict__ A, const unsigned short* __restrict__ Bt,
    const float* __restrict__ bq, const float* __restrict__ bk, const float* __restrict__ bv,
    const float2* __restrict__ tab,
    unsigned short* __restrict__ Qb, unsigned short* __restrict__ Kb,
    unsigned short* __restrict__ Vt) {
  extern __shared__ unsigned char lds[];
  const int tid = threadIdx.x, w = tid >> 6, l = tid & 63;
  const int lg = l >> 4, lm = l & 15;
  const int wc = w;  // 4 waves across N
  const int sw = (blockIdx.x & 7) * 96 + (blockIdx.x >> 3);  // XCD swizzle, 768=8x96
  const int bm = sw / 12, bn = sw % 12;  // bm in [0,64), bn in [0,12)

  f32x4 acc[8][4] = {};

  const unsigned short* Abase = A + (size_t)(bm * 128) * 1024;
  const unsigned short* Bbase = Bt + (size_t)(bn * 256) * 1024;

  auto stageH = [&](int h) {
    unsigned char* db = lds + (h % 3) * 24576;
    const int r = tid & 127, gA = tid >> 7;
    const size_t ko = (size_t)h * 32;
    load_lds16(Abase + (size_t)r * 1024 + ko + gA * 8,       db + tid * 16);
    load_lds16(Abase + (size_t)r * 1024 + ko + (2 + gA) * 8, db + (tid + 256) * 16);
#pragma unroll
    for (int g = 0; g < 4; ++g)
      load_lds16(Bbase + (size_t)tid * 1024 + ko + g * 8, db + 8192 + (g * 256 + tid) * 16);
  };

  stageH(0);
  stageH(1);

  for (int h = 0; h < 32; ++h) {
    if (h == 31) { VMCNT(0); } else { VMCNT(6); }
    SBARL();
    if (h + 2 < 32) stageH(h + 2);
    const unsigned char* slot = lds + (h % 3) * 24576;
    const unsigned char* pa = slot + lg * 2048 + lm * 16;
    const unsigned char* pb = slot + 8192 + lg * 4096 + wc * 1024 + lm * 16;
    bf16x8 af[8], bfr[4];
#pragma unroll
    for (int m = 0; m < 8; ++m) af[m] = *(const bf16x8*)(pa + m * 256);
#pragma unroll
    for (int n = 0; n < 4; ++n) bfr[n] = *(const bf16x8*)(pb + n * 256);
    __builtin_amdgcn_s_setprio(1);
#pragma unroll
    for (int m = 0; m < 8; ++m)
#pragma unroll
      for (int n = 0; n < 4; ++n)
        acc[m][n] = __builtin_amdgcn_mfma_f32_16x16x32_bf16(af[m], bfr[n], acc[m][n], 0, 0, 0);
    __builtin_amdgcn_s_setprio(0);
  }

  const int seg = bn >> 2;  // 0=Q, 1=K, 2=V
  // ---- epilogue phase 1: acc (+bias, bf16-rounded) -> LDS [row:128][col:256]
  __syncthreads();  // all waves done with K-loop LDS reads
  unsigned short* eb = (unsigned short*)lds;
  {
    const float* bias = (seg == 2) ? bv : (seg ? bk : bq);
#pragma unroll
    for (int n = 0; n < 4; ++n) {
      const int colx = wc * 64 + n * 16 + lm;            // tile col 0..255
      const float bvv = bias[((bn & 3) * 256 + colx) & 1023];
#pragma unroll
      for (int m = 0; m < 8; ++m)
#pragma unroll
        for (int i = 0; i < 4; ++i)
          eb[(m * 16 + lg * 4 + i) * 256 + colx] = f2bf(acc[m][n][i] + bvv);
    }
  }
  __syncthreads();
  // ---- epilogue phase 2: coalesced 16B stores
  if (seg != 2) {
    unsigned short* Dst = seg ? Kb : Qb;
    const float qsc = seg ? 1.0f : 0.045084220027780106f;  // log2(e)/32 folded into Q
#pragma unroll
    for (int k = 0; k < 16; ++k) {
      const int u = tid + 256 * k;       // 0..4095
      const int row = u >> 5, cg = u & 31;
      us8 v = *(const us8*)&eb[row * 256 + cg * 8];
      const int grow = bm * 128 + row;
      const int pos = grow & 2047;
      us8 o;
#pragma unroll
      for (int j = 0; j < 4; ++j) {
        const float xe = bf2f(v[2 * j]), xo = bf2f(v[2 * j + 1]);
        const float2 cs = tab[pos * 32 + ((cg & 7) * 4 + j)];
        o[2 * j]     = f2bf((xe * cs.x - xo * cs.y) * qsc);
        o[2 * j + 1] = f2bf((xo * cs.x + xe * cs.y) * qsc);
      }
      *(us8*)&Dst[(size_t)grow * 1024 + (bn & 3) * 256 + cg * 8] = o;
    }
  } else {
#pragma unroll
    for (int k = 0; k < 16; ++k) {
      const int u = tid + 256 * k;
      const int c = u & 255, sg = u >> 8;  // hd-col 0..255, s-chunk 0..15
      us8 o;
#pragma unroll
      for (int e = 0; e < 8; ++e) o[e] = eb[(sg * 8 + e) * 256 + c];
      const int hd = (bn & 3) * 256 + c;
      const int grow = bm * 128 + sg * 8;
      const int bb = grow >> 11, s = grow & 2047;
      *(us8*)&Vt[((size_t)(bb * 1024 + hd)) * 2048 + s] = o;
    }
  }
}

// ---------------- output GEMM: fp32 out + bias; light barriers --------------
__global__ __launch_bounds__(256, 3) void k_gemm_o(const unsigned short* __restrict__ A,
                                                   const unsigned short* __restrict__ Bt,
                                                   const float* __restrict__ bias,
                                                   float* __restrict__ C) {
  __shared__ alignas(16) unsigned short As[3][4096];
  __shared__ alignas(16) unsigned short Bs[3][4096];
  const int tid = threadIdx.x, w = tid >> 6, l = tid & 63;
  const int lg = l >> 4, lm = l & 15;
  const int sw = (blockIdx.x & 7) * 64 + (blockIdx.x >> 3);
  const int bm = sw >> 3, bn = sw & 7;
  const int wr = w >> 1, wc = w & 1;
  f32x4 acc[4][4] = {};
  auto stage = [&](int buf, int kt) {
#pragma unroll
    for (int p = 0; p < 2; ++p) {
      int cb = (w * 2 + p) * 64, c = cb + l, g = c >> 7, r = c & 127;
      load_lds16(A + (size_t)(bm * 128 + r) * 1024 + kt * 32 + g * 8, &As[buf][cb * 8]);
      load_lds16(Bt + (size_t)(bn * 128 + r) * 1024 + kt * 32 + g * 8, &Bs[buf][cb * 8]);
    }
  };
  stage(0, 0);
  stage(1, 1);
  int cur = 0;
  for (int kt = 0; kt < 32; ++kt) {
    if (kt == 31) { VMCNT(0); } else { VMCNT(4); }
    SBARL();
    if (kt + 2 < 32) {
      int nb = cur + 2; if (nb >= 3) nb -= 3;
      stage(nb, kt + 2);
    }
    bf16x8 af[4], bfr[4];
#pragma unroll
    for (int m = 0; m < 4; ++m)
      af[m] = *(const bf16x8*)&As[cur][(lg * 128 + wr * 64 + m * 16 + lm) * 8];
#pragma unroll
    for (int n = 0; n < 4; ++n)
      bfr[n] = *(const bf16x8*)&Bs[cur][(lg * 128 + wc * 64 + n * 16 + lm) * 8];
    __builtin_amdgcn_s_setprio(1);
#pragma unroll
    for (int m = 0; m < 4; ++m)
#pragma unroll
      for (int n = 0; n < 4; ++n)
        acc[m][n] = __builtin_amdgcn_mfma_f32_16x16x32_bf16(af[m], bfr[n], acc[m][n], 0, 0, 0);
    __builtin_amdgcn_s_setprio(0);
    cur = (cur == 2) ? 0 : cur + 1;
  }
  const int row0 = bm * 128 + wr * 64, col0 = bn * 128 + wc * 64;
#pragma unroll
  for (int n = 0; n < 4; ++n) {
    int col = col0 + n * 16 + lm;
    float bv = bias[col];
#pragma unroll
    for (int m = 0; m < 4; ++m) {
      int row = row0 + m * 16 + lg * 4;
#pragma unroll
      for (int i = 0; i < 4; ++i)
        C[(size_t)(row + i) * 1024 + col] = acc[m][n][i] + bv;
    }
  }
}

// ---------------- flash attention (round-11-verbatim) ------------------------
__global__ __launch_bounds__(256, 4) void k_attn(const unsigned short* __restrict__ Q,
                                                 const unsigned short* __restrict__ K,
                                                 const unsigned short* __restrict__ Vt,
                                                 unsigned short* __restrict__ O) {
  __shared__ alignas(16) unsigned short Ks[2][4096];  // [g=kb*4+dc][lane][8]
  __shared__ alignas(16) unsigned short Vs[2][4096];  // [g=kchunk*2+dblk][lane][8]
  const int tid = threadIdx.x, w = tid >> 6, l = tid & 63;
  const int lq = l & 31, hi = l >> 5;
  const int bid = (blockIdx.x & 7) * 128 + (blockIdx.x >> 3);  // XCD swizzle
  const int qt = bid & 15, h = (bid >> 4) & 15, b = bid >> 8;
  const int qrow = qt * 128 + w * 32 + lq;

  const unsigned short* qp = Q + ((size_t)(b * 2048 + qrow)) * 1024 + h * 64 + hi * 8;
  bf16x8 qf[4];
#pragma unroll
  for (int dc = 0; dc < 4; ++dc) qf[dc] = *(const bf16x8*)(qp + dc * 16);

  const unsigned short* Kbase = K + ((size_t)(b * 2048)) * 1024 + h * 64;
  const unsigned short* Vbase = Vt + ((size_t)((b * 16 + h) * 64)) * 2048;
  const int g0 = tid >> 6, ll = tid & 63;
  const size_t koff = ((size_t)((g0 >> 2) * 32 + (ll & 31))) * 1024 + (g0 & 3) * 16 + (ll >> 5) * 8;
  const size_t voff = ((size_t)((g0 & 1) * 32 + (ll & 31))) * 2048 + (g0 >> 1) * 16 + (ll >> 5) * 8;

  auto stageKV = [&](int buf, int tt) {
    const size_t kb = (size_t)(tt * 64) * 1024;
    load_lds16(Kbase + kb + koff, &Ks[buf][tid * 8]);
    load_lds16(Kbase + kb + koff + (size_t)32 * 1024, &Ks[buf][(tid + 256) * 8]);
    load_lds16(Vbase + tt * 64 + voff, &Vs[buf][tid * 8]);
    load_lds16(Vbase + tt * 64 + voff + 32, &Vs[buf][(tid + 256) * 8]);
  };

  float L = 0.0f;
  f32x16 Oa0 = {}, Oa1 = {};

  stageKV(0, 0);
  __syncthreads();

  for (int t = 0; t < 32; ++t) {
    const int cur = t & 1;
    if (t < 31) stageKV(cur ^ 1, t + 1);  // issue early; drain at iter end
    // S[key][query]
    f32x16 s0 = {}, s1 = {};
    const unsigned short* Kc = Ks[cur];
    __builtin_amdgcn_s_setprio(1);
#pragma unroll
    for (int dc = 0; dc < 4; ++dc) {
      bf16x8 kf0 = *(const bf16x8*)&Kc[(dc * 64 + l) * 8];
      bf16x8 kf1 = *(const bf16x8*)&Kc[((4 + dc) * 64 + l) * 8];
      s0 = __builtin_amdgcn_mfma_f32_32x32x16_bf16(kf0, qf[dc], s0, 0, 0, 0);
      s1 = __builtin_amdgcn_mfma_f32_32x32x16_bf16(kf1, qf[dc], s1, 0, 0, 0);
    }
    __builtin_amdgcn_s_setprio(0);
    // p = 2^s directly — single v_exp_f32 per element (scores bounded, no shift)
#pragma unroll
    for (int r = 0; r < 16; ++r) s0[r] = fexp2(s0[r]);
#pragma unroll
    for (int r = 0; r < 16; ++r) s1[r] = fexp2(s1[r]);
    // balanced tree sum
    float q8[8];
#pragma unroll
    for (int j = 0; j < 8; ++j) q8[j] = (s0[j] + s0[j + 8]) + (s1[j] + s1[j + 8]);
#pragma unroll
    for (int j = 0; j < 4; ++j) q8[j] += q8[j + 4];
    float ls = (q8[0] + q8[1]) + (q8[2] + q8[3]);
    ls += __shfl_xor(ls, 32, 64);
    L += ls;
    // pack P to bf16 pairs
    unsigned w0[8], w1[8];
#pragma unroll
    for (int j = 0; j < 8; ++j) {
      w0[j] = pk2(s0[2 * j], s0[2 * j + 1]);
      w1[j] = pk2(s1[2 * j], s1[2 * j + 1]);
    }
    // exchange halves with lane^32 to build B-frags
    unsigned ra = __shfl_xor(hi ? w0[0] : w0[2], 32, 64);
    unsigned rb = __shfl_xor(hi ? w0[1] : w0[3], 32, 64);
    unsigned rc = __shfl_xor(hi ? w0[4] : w0[6], 32, 64);
    unsigned rd = __shfl_xor(hi ? w0[5] : w0[7], 32, 64);
    unsigned re = __shfl_xor(hi ? w1[0] : w1[2], 32, 64);
    unsigned rf = __shfl_xor(hi ? w1[1] : w1[3], 32, 64);
    unsigned rg = __shfl_xor(hi ? w1[4] : w1[6], 32, 64);
    unsigned rh = __shfl_xor(hi ? w1[5] : w1[7], 32, 64);
    bf16x8 pf0 = hi ? frag4(ra, rb, w0[2], w0[3]) : frag4(w0[0], w0[1], ra, rb);
    bf16x8 pf1 = hi ? frag4(rc, rd, w0[6], w0[7]) : frag4(w0[4], w0[5], rc, rd);
    bf16x8 pf2 = hi ? frag4(re, rf, w1[2], w1[3]) : frag4(w1[0], w1[1], re, rf);
    bf16x8 pf3 = hi ? frag4(rg, rh, w1[6], w1[7]) : frag4(w1[4], w1[5], rg, rh);
    // O^T[d][query] += V^T[d][key] * P[key][query]
    const unsigned short* Vc = Vs[cur];
    __builtin_amdgcn_s_setprio(1);
    {
      bf16x8 v0 = *(const bf16x8*)&Vc[(0 * 64 + l) * 8];
      bf16x8 v1 = *(const bf16x8*)&Vc[(1 * 64 + l) * 8];
      Oa0 = __builtin_amdgcn_mfma_f32_32x32x16_bf16(v0, pf0, Oa0, 0, 0, 0);
      Oa1 = __builtin_amdgcn_mfma_f32_32x32x16_bf16(v1, pf0, Oa1, 0, 0, 0);
      v0 = *(const bf16x8*)&Vc[(2 * 64 + l) * 8];
      v1 = *(const bf16x8*)&Vc[(3 * 64 + l) * 8];
      Oa0 = __builtin_amdgcn_mfma_f32_32x32x16_bf16(v0, pf1, Oa0, 0, 0, 0);
      Oa1 = __builtin_amdgcn_mfma_f32_32x32x16_bf16(v1, pf1, Oa1, 0, 0, 0);
      v0 = *(const bf16x8*)&Vc[(4 * 64 + l) * 8];
      v1 = *(const bf16x8*)&Vc[(5 * 64 + l) * 8];
      Oa0 = __builtin_amdgcn_mfma_f32_32x32x16_bf16(v0, pf2, Oa0, 0, 0, 0);
      Oa1 = __builtin_amdgcn_mfma_f32_32x32x16_bf16(v1, pf2, Oa1, 0, 0, 0);
      v0 = *(const bf16x8*)&Vc[(6 * 64 + l) * 8];
      v1 = *(const bf16x8*)&Vc[(7 * 64 + l) * 8];
      Oa0 = __builtin_amdgcn_mfma_f32_32x32x16_bf16(v0, pf3, Oa0, 0, 0, 0);
      Oa1 = __builtin_amdgcn_mfma_f32_32x32x16_bf16(v1, pf3, Oa1, 0, 0, 0);
    }
    __builtin_amdgcn_s_setprio(0);
    if (t < 31) __syncthreads();  // drains stage(t+1) + guards buffer reuse
  }
  const float inv = 1.0f / L;
  unsigned short* op = O + ((size_t)(b * 2048 + qrow)) * 1024 + h * 64;
#pragma unroll
  for (int gq = 0; gq < 4; ++gq) {
    const int d0 = 8 * gq + 4 * hi;
    us4 o0, o1;
#pragma unroll
    for (int i = 0; i < 4; ++i) {
      o0[i] = f2bf(Oa0[gq * 4 + i] * inv);
      o1[i] = f2bf(Oa1[gq * 4 + i] * inv);
    }
    *(us4*)&op[d0] = o0;
    *(us4*)&op[32 + d0] = o1;
  }
}

extern "C" void kernel_launch(void* const* d_in, const int* in_sizes, int n_in,
                              void* d_out, int out_size, void* d_ws, size_t ws_size,
                              hipStream_t stream) {
  const float* x  = (const float*)d_in[0];
  const float* Wq = (const float*)d_in[1];
  const float* bq = (const float*)d_in[2];
  const float* Wk = (const float*)d_in[3];
  const float* bk = (const float*)d_in[4];
  const float* Wv = (const float*)d_in[5];
  const float* bv = (const float*)d_in[6];
  const float* Wo = (const float*)d_in[7];
  const float* bo = (const float*)d_in[8];

  unsigned short* xb   = (unsigned short*)d_ws;             // 8192x1024 bf16
  unsigned short* Wqkv = xb + (size_t)8192 * 1024;          // 3072x1024 bf16 (Q;K;V rows)
  unsigned short* WoT  = Wqkv + (size_t)3072 * 1024;        // 1024x1024
  unsigned short* Qb   = WoT + (size_t)1024 * 1024;         // 8192x1024
  unsigned short* Kb   = Qb + (size_t)8192 * 1024;
  unsigned short* Vt   = Kb + (size_t)8192 * 1024;          // [b][h*64+d][2048]
  unsigned short* Ib   = Vt + (size_t)8192 * 1024;          // attn out
  float2* tab = (float2*)Ib;  // 512KB rope table; dead before k_attn overwrites Ib

  k_prep<<<5376, 256, 0, stream>>>(x, xb, tab, Wq, Wk, Wv, Wo,
                                   Wqkv, Wqkv + (size_t)1024 * 1024,
                                   Wqkv + (size_t)2048 * 1024, WoT);
  k_gemm_qkv<<<768, 256, 73728, stream>>>(xb, Wqkv, bq, bk, bv, tab, Qb, Kb, Vt);
  k_attn<<<1024, 256, 0, stream>>>(Qb, Kb, Vt, Ib);
  k_gemm_o<<<512, 256, 0, stream>>>(Ib, WoT, bo, (float*)d_out);
}